// Round 3
// baseline (2542.494 us; speedup 1.0000x reference)
//
#include <hip/hip_runtime.h>
#include <hip/hip_bf16.h>
#include <stdint.h>

// SpMiddleNoDownsampleXYNoExpand on MI355X.
// sparse scatter -> subM conv(16->32) -> subM conv(32->64) [fp32]
// -> pool1 (to bf16) -> 3x MFMA conv64 -> pool2 -> 3x MFMA conv64 -> pool3 -> f32 out.

#define EPS 1e-3f
constexpr int Dd = 41, Hh = 160, Ww = 160;
constexpr int D1 = 21, D2 = 10;

typedef short bf16x8 __attribute__((ext_vector_type(8)));
typedef float f32x4  __attribute__((ext_vector_type(4)));

// ---- winner scatter (last-write-wins == max voxel index) ----
__global__ void k_scatter_winner(const int* __restrict__ coors, int* __restrict__ map, int N) {
    int i = blockIdx.x * blockDim.x + threadIdx.x;
    if (i >= N) return;
    int z = coors[i*4+1], y = coors[i*4+2], x = coors[i*4+3];
    atomicMax(&map[(z*Hh + y)*Ww + x], i);
}

// ---- sparse submanifold conv 16->32 + BN0 + ReLU (fp32) ----
__global__ void k_conv1(const float* __restrict__ feat, const int* __restrict__ coors,
                        const int* __restrict__ map, const float* __restrict__ w,
                        const float* __restrict__ g, const float* __restrict__ b,
                        const float* __restrict__ mn, const float* __restrict__ vr,
                        float* __restrict__ y1, int N) {
    int t = blockIdx.x * blockDim.x + threadIdx.x;
    int i = t >> 5, oc = t & 31;
    if (i >= N) return;
    int z = coors[i*4+1], yy = coors[i*4+2], xx = coors[i*4+3];
    int cell = (z*Hh + yy)*Ww + xx;
    if (map[cell] != i) return;
    float acc = 0.f;
    for (int dz = 0; dz < 3; ++dz) {
        int nz = z + dz - 1; if (nz < 0 || nz >= Dd) continue;
        for (int dy = 0; dy < 3; ++dy) {
            int ny = yy + dy - 1; if (ny < 0 || ny >= Hh) continue;
            for (int dx = 0; dx < 3; ++dx) {
                int nx = xx + dx - 1; if (nx < 0 || nx >= Ww) continue;
                int j = map[(nz*Hh + ny)*Ww + nx];
                if (j < 0) continue;
                const float* f = feat + j*16;
                const float* wp = w + ((dz*3+dy)*3+dx)*(16*32) + oc;
                #pragma unroll
                for (int ic = 0; ic < 16; ++ic)
                    acc += f[ic] * wp[ic*32];
            }
        }
    }
    float s = g[oc] * rsqrtf(vr[oc] + EPS);
    y1[i*32 + oc] = fmaxf((acc - mn[oc]) * s + b[oc], 0.f);
}

// ---- sparse submanifold conv 32->64 + BN(row0) + ReLU (fp32) ----
__global__ void k_conv2(const float* __restrict__ y1, const int* __restrict__ coors,
                        const int* __restrict__ map, const float* __restrict__ w,
                        const float* __restrict__ g, const float* __restrict__ b,
                        const float* __restrict__ mn, const float* __restrict__ vr,
                        float* __restrict__ y2, int N) {
    int t = blockIdx.x * blockDim.x + threadIdx.x;
    int i = t >> 6, oc = t & 63;
    if (i >= N) return;
    int z = coors[i*4+1], yy = coors[i*4+2], xx = coors[i*4+3];
    int cell = (z*Hh + yy)*Ww + xx;
    if (map[cell] != i) return;
    float acc = 0.f;
    for (int dz = 0; dz < 3; ++dz) {
        int nz = z + dz - 1; if (nz < 0 || nz >= Dd) continue;
        for (int dy = 0; dy < 3; ++dy) {
            int ny = yy + dy - 1; if (ny < 0 || ny >= Hh) continue;
            for (int dx = 0; dx < 3; ++dx) {
                int nx = xx + dx - 1; if (nx < 0 || nx >= Ww) continue;
                int j = map[(nz*Hh + ny)*Ww + nx];
                if (j < 0) continue;
                const float* f = y1 + j*32;
                const float* wp = w + ((dz*3+dy)*3+dx)*(32*64) + oc;
                #pragma unroll
                for (int ic = 0; ic < 32; ++ic)
                    acc += f[ic] * wp[ic*64];
            }
        }
    }
    float s = g[oc] * rsqrtf(vr[oc] + EPS);
    y2[i*64 + oc] = fmaxf((acc - mn[oc]) * s + b[oc], 0.f);
}

// ---- pool1 (3,3,3)/(2,1,1)/pad(1,1,1) over sparse y2 + BN(row1) + ReLU -> bf16 ----
__global__ void k_pool1(const float* __restrict__ y2, const int* __restrict__ map,
                        const float* __restrict__ g, const float* __restrict__ b,
                        const float* __restrict__ mn, const float* __restrict__ vr,
                        __hip_bfloat16* __restrict__ p, uint8_t* __restrict__ mk) {
    int t = blockIdx.x * blockDim.x + threadIdx.x;
    int c = t & 63, vox = t >> 6;
    if (vox >= D1*Hh*Ww) return;
    int x = vox % Ww, y = (vox / Ww) % Hh, zo = vox / (Ww*Hh);
    float mval = -1e30f; bool any = false;
    for (int dz = 0; dz < 3; ++dz) {
        int zi = 2*zo + dz - 1; if (zi < 0 || zi >= Dd) continue;
        for (int dy = -1; dy <= 1; ++dy) {
            int yi = y + dy; if (yi < 0 || yi >= Hh) continue;
            for (int dx = -1; dx <= 1; ++dx) {
                int xi = x + dx; if (xi < 0 || xi >= Ww) continue;
                int j = map[(zi*Hh + yi)*Ww + xi];
                if (j < 0) continue;
                any = true;
                mval = fmaxf(mval, y2[j*64 + c]);
            }
        }
    }
    float out = 0.f;
    if (any) {
        float s = g[c] * rsqrtf(vr[c] + EPS);
        out = fmaxf((mval - mn[c]) * s + b[c], 0.f);
    }
    p[(size_t)vox*64 + c] = __float2bfloat16(out);
    if (c == 0) mk[vox] = any ? 1 : 0;
}

// ---- weight pack: w_mid[L][t][ic][oc] f32 -> per-lane-contiguous bf16 fragments ----
// wp[((((L*27+t)*2+h)*4+n)*64+lane)*8+j] = bf16(w[L][t][h*32+(lane>>4)*8+j][n*16+(lane&15)])
__global__ void k_pack_w(const float* __restrict__ w, __hip_bfloat16* __restrict__ wp, int total) {
    int idx = blockIdx.x * blockDim.x + threadIdx.x;
    if (idx >= total) return;
    int j    = idx & 7;
    int lane = (idx >> 3) & 63;
    int n    = (idx >> 9) & 3;
    int h    = (idx >> 11) & 1;
    int rest = idx >> 12;
    int t    = rest % 27;
    int L    = rest / 27;
    int ic = h*32 + (lane >> 4)*8 + j;
    int oc = n*16 + (lane & 15);
    wp[idx] = __float2bfloat16(w[((size_t)(L*27 + t)*64 + ic)*64 + oc]);
}

// ---- dense 3x3x3 conv 64->64 via MFMA + BN + ReLU + mask, bf16 in/out ----
// Block: 256 thr = 4 waves. Block tile: 32x * 8y * 1z. Wave w: rows y0+2w, y0+2w+1,
// M=64 positions (4 A-frags: (ry,rx) = (f>>1, f&1)), N=64 oc (4 B-tiles).
// K = 27 taps * 2 ic-halves, each a 16x16x32 bf16 MFMA per (f,n).
template<int DD>
__global__ __launch_bounds__(256) void k_conv64_mfma(
        const __hip_bfloat16* __restrict__ in, const __hip_bfloat16* __restrict__ wpL,
        const uint8_t* __restrict__ mask,
        const float* __restrict__ g, const float* __restrict__ b,
        const float* __restrict__ mn, const float* __restrict__ vr,
        __hip_bfloat16* __restrict__ out) {
    const int tid = threadIdx.x;
    const int w = tid >> 6, l = tid & 63;
    const int l15 = l & 15, kg = l >> 4;
    const int x0 = blockIdx.x * 32, yb = blockIdx.y * 8 + 2*w, z = blockIdx.z;

    f32x4 acc[4][4];
    #pragma unroll
    for (int f = 0; f < 4; ++f)
        #pragma unroll
        for (int n = 0; n < 4; ++n)
            acc[f][n] = (f32x4){0.f, 0.f, 0.f, 0.f};

    const bf16x8 az = {0,0,0,0,0,0,0,0};
    int t = 0;
    for (int kz = 0; kz < 3; ++kz) {
        const int zi = z + kz - 1;
        const bool zok = (zi >= 0) && (zi < DD);
        for (int ky = 0; ky < 3; ++ky) {
            for (int kx = 0; kx < 3; ++kx, ++t) {
                #pragma unroll
                for (int h = 0; h < 2; ++h) {
                    // B fragments (always in-bounds)
                    bf16x8 bfr[4];
                    const __hip_bfloat16* wb = wpL + (size_t)(t*2 + h)*2048 + (size_t)l*8;
                    #pragma unroll
                    for (int n = 0; n < 4; ++n)
                        bfr[n] = *reinterpret_cast<const bf16x8*>(wb + n*512);
                    // A fragments (predicated on grid bounds)
                    bf16x8 afr[4];
                    #pragma unroll
                    for (int f = 0; f < 4; ++f) {
                        int yi = yb + (f >> 1) + ky - 1;
                        int xi = x0 + (f & 1)*16 + l15 + kx - 1;
                        bool ok = zok && (unsigned)yi < (unsigned)Hh && (unsigned)xi < (unsigned)Ww;
                        if (ok) {
                            const __hip_bfloat16* ap =
                                in + ((size_t)(zi*Hh + yi)*Ww + xi)*64 + h*32 + kg*8;
                            afr[f] = *reinterpret_cast<const bf16x8*>(ap);
                        } else {
                            afr[f] = az;
                        }
                    }
                    #pragma unroll
                    for (int f = 0; f < 4; ++f)
                        #pragma unroll
                        for (int n = 0; n < 4; ++n)
                            acc[f][n] = __builtin_amdgcn_mfma_f32_16x16x32_bf16(
                                afr[f], bfr[n], acc[f][n], 0, 0, 0);
                }
            }
        }
    }

    // BN scale/shift for this lane's 4 oc (oc = n*16 + l15)
    float sc[4], sh[4];
    #pragma unroll
    for (int n = 0; n < 4; ++n) {
        int oc = n*16 + l15;
        float s = g[oc] * rsqrtf(vr[oc] + EPS);
        sc[n] = s; sh[n] = b[oc] - mn[oc]*s;
    }
    // D layout: lane l, reg r -> position m = kg*4 + r (within frag), oc-col = l15.
    #pragma unroll
    for (int f = 0; f < 4; ++f) {
        int yv = yb + (f >> 1);
        int xb2 = x0 + (f & 1)*16 + kg*4;
        #pragma unroll
        for (int r = 0; r < 4; ++r) {
            int vox = (z*Hh + yv)*Ww + (xb2 + r);
            bool mk = mask[vox] != 0;
            #pragma unroll
            for (int n = 0; n < 4; ++n) {
                float v = mk ? fmaxf(acc[f][n][r]*sc[n] + sh[n], 0.f) : 0.f;
                out[(size_t)vox*64 + n*16 + l15] = __float2bfloat16(v);
            }
        }
    }
}

// ---- pool2 (3,3,3)/(2,1,1)/pad(0,1,1) + BN(row5) + ReLU, bf16 in/out ----
__global__ void k_pool2(const __hip_bfloat16* __restrict__ in, const uint8_t* __restrict__ mki,
                        const float* __restrict__ g, const float* __restrict__ b,
                        const float* __restrict__ mn, const float* __restrict__ vr,
                        __hip_bfloat16* __restrict__ p, uint8_t* __restrict__ mk) {
    int t = blockIdx.x * blockDim.x + threadIdx.x;
    int c = t & 63, vox = t >> 6;
    if (vox >= D2*Hh*Ww) return;
    int x = vox % Ww, y = (vox / Ww) % Hh, zo = vox / (Ww*Hh);
    float mval = -1e30f; bool any = false;
    for (int dz = 0; dz < 3; ++dz) {
        int zi = 2*zo + dz;                 // always in [0,21)
        for (int dy = -1; dy <= 1; ++dy) {
            int yi = y + dy; if (yi < 0 || yi >= Hh) continue;
            for (int dx = -1; dx <= 1; ++dx) {
                int xi = x + dx; if (xi < 0 || xi >= Ww) continue;
                int cv = (zi*Hh + yi)*Ww + xi;
                if (mki[cv]) {
                    any = true;
                    mval = fmaxf(mval, __bfloat162float(in[(size_t)cv*64 + c]));
                }
            }
        }
    }
    float out = 0.f;
    if (any) {
        float s = g[c] * rsqrtf(vr[c] + EPS);
        out = fmaxf((mval - mn[c]) * s + b[c], 0.f);
    }
    p[(size_t)vox*64 + c] = __float2bfloat16(out);
    if (c == 0) mk[vox] = any ? 1 : 0;
}

// ---- pool3 (3,1,1)/(2,1,1)/pad0 + BN(row9) + ReLU + transpose -> f32 (C*4,H,W) ----
__global__ void k_pool3(const __hip_bfloat16* __restrict__ in, const uint8_t* __restrict__ mki,
                        const float* __restrict__ g, const float* __restrict__ b,
                        const float* __restrict__ mn, const float* __restrict__ vr,
                        float* __restrict__ out) {
    int t = blockIdx.x * blockDim.x + threadIdx.x;
    if (t >= 64*4*Hh*Ww) return;
    int x = t % Ww, y = (t / Ww) % Hh, zo = (t / (Ww*Hh)) & 3, c = t / (Ww*Hh*4);
    float mval = -1e30f; bool any = false;
    for (int dz = 0; dz < 3; ++dz) {
        int zi = 2*zo + dz;                 // max 8 < 10
        int cv = (zi*Hh + y)*Ww + x;
        if (mki[cv]) {
            any = true;
            mval = fmaxf(mval, __bfloat162float(in[(size_t)cv*64 + c]));
        }
    }
    float o = 0.f;
    if (any) {
        float s = g[c] * rsqrtf(vr[c] + EPS);
        o = fmaxf((mval - mn[c]) * s + b[c], 0.f);
    }
    out[t] = o;   // t == ((c*4+zo)*Hh + y)*Ww + x  -> transposed layout
}

extern "C" void kernel_launch(void* const* d_in, const int* in_sizes, int n_in,
                              void* d_out, int out_size, void* d_ws, size_t ws_size,
                              hipStream_t stream) {
    const float* vf    = (const float*)d_in[0];
    const int*   coors = (const int*)  d_in[1];
    const float* w_in  = (const float*)d_in[3];
    const float* w_up  = (const float*)d_in[4];
    const float* w_mid = (const float*)d_in[5];
    const float* bn0_g = (const float*)d_in[6];
    const float* bn0_b = (const float*)d_in[7];
    const float* bn0_m = (const float*)d_in[8];
    const float* bn0_v = (const float*)d_in[9];
    const float* bn_g  = (const float*)d_in[10];
    const float* bn_b  = (const float*)d_in[11];
    const float* bn_m  = (const float*)d_in[12];
    const float* bn_v  = (const float*)d_in[13];
    const int N = in_sizes[0] / 16;

    char* ws = (char*)d_ws;
    size_t off = 0;
    auto alloc = [&](size_t bytes) {
        void* p = ws + off;
        off = (off + bytes + 255) & ~(size_t)255;
        return p;
    };
    int*            map = (int*)            alloc((size_t)Dd*Hh*Ww*4);
    float*          y1  = (float*)          alloc((size_t)N*32*4);
    float*          y2  = (float*)          alloc((size_t)N*64*4);
    uint8_t*        mk1 = (uint8_t*)        alloc((size_t)D1*Hh*Ww);
    uint8_t*        mk2 = (uint8_t*)        alloc((size_t)D2*Hh*Ww);
    __hip_bfloat16* wp  = (__hip_bfloat16*) alloc((size_t)6*27*2*4*64*8*2);
    __hip_bfloat16* A   = (__hip_bfloat16*) alloc((size_t)D1*Hh*Ww*64*2);
    __hip_bfloat16* B   = (__hip_bfloat16*) alloc((size_t)D1*Hh*Ww*64*2);

    const int PACK_TOTAL = 6*27*2*4*64*8;          // 663552
    const size_t WPL = (size_t)27*2*4*64*8;        // 110592 elems per layer

    hipMemsetAsync(map, 0xFF, (size_t)Dd*Hh*Ww*4, stream);
    k_pack_w<<<(PACK_TOTAL + 255)/256, 256, 0, stream>>>(w_mid, wp, PACK_TOTAL);
    k_scatter_winner<<<(N + 255)/256, 256, 0, stream>>>(coors, map, N);
    k_conv1<<<(N*32 + 255)/256, 256, 0, stream>>>(vf, coors, map, w_in,
            bn0_g, bn0_b, bn0_m, bn0_v, y1, N);
    k_conv2<<<(N*64 + 255)/256, 256, 0, stream>>>(y1, coors, map, w_up,
            bn_g, bn_b, bn_m, bn_v, y2, N);
    k_pool1<<<(D1*Hh*Ww*64 + 255)/256, 256, 0, stream>>>(y2, map,
            bn_g + 64, bn_b + 64, bn_m + 64, bn_v + 64, A, mk1);

    dim3 g1(Ww/32, Hh/8, D1);
    k_conv64_mfma<D1><<<g1, 256, 0, stream>>>(A, wp + 0*WPL, mk1,
            bn_g + 2*64, bn_b + 2*64, bn_m + 2*64, bn_v + 2*64, B);
    k_conv64_mfma<D1><<<g1, 256, 0, stream>>>(B, wp + 1*WPL, mk1,
            bn_g + 3*64, bn_b + 3*64, bn_m + 3*64, bn_v + 3*64, A);
    k_conv64_mfma<D1><<<g1, 256, 0, stream>>>(A, wp + 2*WPL, mk1,
            bn_g + 4*64, bn_b + 4*64, bn_m + 4*64, bn_v + 4*64, B);

    k_pool2<<<(D2*Hh*Ww*64 + 255)/256, 256, 0, stream>>>(B, mk1,
            bn_g + 5*64, bn_b + 5*64, bn_m + 5*64, bn_v + 5*64, A, mk2);

    dim3 g2(Ww/32, Hh/8, D2);
    k_conv64_mfma<D2><<<g2, 256, 0, stream>>>(A, wp + 3*WPL, mk2,
            bn_g + 6*64, bn_b + 6*64, bn_m + 6*64, bn_v + 6*64, B);
    k_conv64_mfma<D2><<<g2, 256, 0, stream>>>(B, wp + 4*WPL, mk2,
            bn_g + 7*64, bn_b + 7*64, bn_m + 7*64, bn_v + 7*64, A);
    k_conv64_mfma<D2><<<g2, 256, 0, stream>>>(A, wp + 5*WPL, mk2,
            bn_g + 8*64, bn_b + 8*64, bn_m + 8*64, bn_v + 8*64, B);

    k_pool3<<<(64*4*Hh*Ww + 255)/256, 256, 0, stream>>>(B, mk2,
            bn_g + 9*64, bn_b + 9*64, bn_m + 9*64, bn_v + 9*64, (float*)d_out);
}

// Round 8
// 1856.489 us; speedup vs baseline: 1.3695x; 1.3695x over previous
//
#include <hip/hip_runtime.h>
#include <hip/hip_bf16.h>
#include <stdint.h>

// SpMiddleNoDownsampleXYNoExpand on MI355X.
// sparse scatter -> subM conv(16->32) -> subM conv(32->64) [fp32]
// -> sparse z-gather pool1 + separable y/x -> 3x MFMA conv64 -> separable pool2
// -> 3x MFMA conv64 -> pool3(z)+transpose -> f32 out.
// Workspace kept at ~175 MB (round-3 proven size); no dense 41-grid.

#define EPS 1e-3f
constexpr int Dd = 41, Hh = 160, Ww = 160;
constexpr int D1 = 21, D2 = 10;

typedef short bf16x8 __attribute__((ext_vector_type(8)));
typedef short short8 __attribute__((ext_vector_type(8)));
typedef float f32x4  __attribute__((ext_vector_type(4)));

static __device__ __forceinline__ short f2bfs(float f) {
    __hip_bfloat16 h = __float2bfloat16(f);
    return *reinterpret_cast<short*>(&h);
}
static __device__ __forceinline__ float bfs2f(short s) {
    union { unsigned u; float f; } cv;
    cv.u = ((unsigned)(unsigned short)s) << 16;
    return cv.f;
}
static __device__ __forceinline__ short8 smax8(short8 a, short8 b) {
    short8 r;
    #pragma unroll
    for (int j = 0; j < 8; ++j) r[j] = a[j] > b[j] ? a[j] : b[j];
    return r;
}

// ---- winner scatter (last-write-wins == max voxel index) ----
__global__ void k_scatter_winner(const int* __restrict__ coors, int* __restrict__ map, int N) {
    int i = blockIdx.x * blockDim.x + threadIdx.x;
    if (i >= N) return;
    int z = coors[i*4+1], y = coors[i*4+2], x = coors[i*4+3];
    atomicMax(&map[(z*Hh + y)*Ww + x], i);
}

// ---- sparse submanifold conv 16->32 + BN0 + ReLU (fp32) ----
__global__ void k_conv1(const float* __restrict__ feat, const int* __restrict__ coors,
                        const int* __restrict__ map, const float* __restrict__ w,
                        const float* __restrict__ g, const float* __restrict__ b,
                        const float* __restrict__ mn, const float* __restrict__ vr,
                        float* __restrict__ y1, int N) {
    int t = blockIdx.x * blockDim.x + threadIdx.x;
    int i = t >> 5, oc = t & 31;
    if (i >= N) return;
    int z = coors[i*4+1], yy = coors[i*4+2], xx = coors[i*4+3];
    int cell = (z*Hh + yy)*Ww + xx;
    if (map[cell] != i) return;
    float acc = 0.f;
    for (int dz = 0; dz < 3; ++dz) {
        int nz = z + dz - 1; if (nz < 0 || nz >= Dd) continue;
        for (int dy = 0; dy < 3; ++dy) {
            int ny = yy + dy - 1; if (ny < 0 || ny >= Hh) continue;
            for (int dx = 0; dx < 3; ++dx) {
                int nx = xx + dx - 1; if (nx < 0 || nx >= Ww) continue;
                int j = map[(nz*Hh + ny)*Ww + nx];
                if (j < 0) continue;
                const float* f = feat + j*16;
                const float* wp = w + ((dz*3+dy)*3+dx)*(16*32) + oc;
                #pragma unroll
                for (int ic = 0; ic < 16; ++ic)
                    acc += f[ic] * wp[ic*32];
            }
        }
    }
    float s = g[oc] * rsqrtf(vr[oc] + EPS);
    y1[i*32 + oc] = fmaxf((acc - mn[oc]) * s + b[oc], 0.f);
}

// ---- sparse submanifold conv 32->64 + BN(row0) + ReLU (fp32) ----
__global__ void k_conv2(const float* __restrict__ y1, const int* __restrict__ coors,
                        const int* __restrict__ map, const float* __restrict__ w,
                        const float* __restrict__ g, const float* __restrict__ b,
                        const float* __restrict__ mn, const float* __restrict__ vr,
                        float* __restrict__ y2, int N) {
    int t = blockIdx.x * blockDim.x + threadIdx.x;
    int i = t >> 6, oc = t & 63;
    if (i >= N) return;
    int z = coors[i*4+1], yy = coors[i*4+2], xx = coors[i*4+3];
    int cell = (z*Hh + yy)*Ww + xx;
    if (map[cell] != i) return;
    float acc = 0.f;
    for (int dz = 0; dz < 3; ++dz) {
        int nz = z + dz - 1; if (nz < 0 || nz >= Dd) continue;
        for (int dy = 0; dy < 3; ++dy) {
            int ny = yy + dy - 1; if (ny < 0 || ny >= Hh) continue;
            for (int dx = 0; dx < 3; ++dx) {
                int nx = xx + dx - 1; if (nx < 0 || nx >= Ww) continue;
                int j = map[(nz*Hh + ny)*Ww + nx];
                if (j < 0) continue;
                const float* f = y1 + j*32;
                const float* wp = w + ((dz*3+dy)*3+dx)*(32*64) + oc;
                #pragma unroll
                for (int ic = 0; ic < 32; ++ic)
                    acc += f[ic] * wp[ic*64];
            }
        }
    }
    float s = g[oc] * rsqrtf(vr[oc] + EPS);
    y2[i*64 + oc] = fmaxf((acc - mn[oc]) * s + b[oc], 0.f);
}

// ---- pool1 z-pass as sparse gather: (41 -> 21) via map, winner rows of fp32 y2.
// Output: dense D1 bf16 grid; empty cells = bf16 -inf (0xFF80). 8 threads/voxel.
__global__ void k_p1zg(const float* __restrict__ y2, const int* __restrict__ map,
                       short8* __restrict__ out) {
    int t = blockIdx.x * blockDim.x + threadIdx.x;
    if (t >= D1*Hh*Ww*8) return;
    int c8 = t & 7, vox = t >> 3;
    int x = vox % Ww, y = (vox / Ww) % Hh, zo = vox / (Ww*Hh);
    float mv[8];
    #pragma unroll
    for (int q = 0; q < 8; ++q) mv[q] = 0.f;   // y2 >= 0 (post-ReLU), so 0-init is safe
    bool any = false;
    for (int dz = 0; dz < 3; ++dz) {
        int zi = 2*zo + dz - 1;
        if ((unsigned)zi >= (unsigned)Dd) continue;
        int j = map[(zi*Hh + y)*Ww + x];
        if (j < 0) continue;
        any = true;
        const float4* f = reinterpret_cast<const float4*>(y2 + (size_t)j*64 + c8*8);
        float4 a = f[0], b = f[1];
        mv[0] = fmaxf(mv[0], a.x); mv[1] = fmaxf(mv[1], a.y);
        mv[2] = fmaxf(mv[2], a.z); mv[3] = fmaxf(mv[3], a.w);
        mv[4] = fmaxf(mv[4], b.x); mv[5] = fmaxf(mv[5], b.y);
        mv[6] = fmaxf(mv[6], b.z); mv[7] = fmaxf(mv[7], b.w);
    }
    short8 o;
    #pragma unroll
    for (int q = 0; q < 8; ++q) o[q] = any ? f2bfs(mv[q]) : (short)0xFF80;
    out[(size_t)vox*8 + c8] = o;
}

// ---- pool1 y-pass (int16 max; -inf encodes empty) ----
__global__ void k_p1y(const short8* __restrict__ in, short8* __restrict__ out) {
    int t = blockIdx.x * blockDim.x + threadIdx.x;
    if (t >= D1*Hh*Ww*8) return;
    int c8 = t & 7, vox = t >> 3;
    int x = vox % Ww, y = (vox / Ww) % Hh, zo = vox / (Ww*Hh);
    size_t base = ((size_t)zo*Hh*Ww)*8;
    short8 m = in[base + ((size_t)y*Ww + x)*8 + c8];
    if (y > 0)      m = smax8(m, in[base + ((size_t)(y-1)*Ww + x)*8 + c8]);
    if (y < Hh-1)   m = smax8(m, in[base + ((size_t)(y+1)*Ww + x)*8 + c8]);
    out[(size_t)vox*8 + c8] = m;
}

// ---- pool1 x-pass + BN(row1) + ReLU + mask; mask = (max >= 0) since empty == -inf ----
__global__ void k_p1x(const short8* __restrict__ in,
                      const float* __restrict__ g, const float* __restrict__ b,
                      const float* __restrict__ mn, const float* __restrict__ vr,
                      short8* __restrict__ out, uint8_t* __restrict__ mk) {
    int t = blockIdx.x * blockDim.x + threadIdx.x;
    if (t >= D1*Hh*Ww*8) return;
    int c8 = t & 7, vox = t >> 3;
    int x = vox % Ww;
    short8 m = in[(size_t)vox*8 + c8];
    if (x > 0)      m = smax8(m, in[(size_t)(vox-1)*8 + c8]);
    if (x < Ww-1)   m = smax8(m, in[(size_t)(vox+1)*8 + c8]);
    bool occ = m[0] >= 0;     // occupied => all channels >= 0; empty => all -inf
    short8 o;
    #pragma unroll
    for (int j = 0; j < 8; ++j) {
        float v = 0.f;
        if (occ) {
            int c = c8*8 + j;
            float s = g[c] * rsqrtf(vr[c] + EPS);
            v = fmaxf(bfs2f(m[j])*s + (b[c] - mn[c]*s), 0.f);
        }
        o[j] = f2bfs(v);
    }
    out[(size_t)vox*8 + c8] = o;
    if (c8 == 0) mk[vox] = occ ? 1 : 0;
}

// ---- weight pack: w_mid[L][t][ic][oc] f32 -> per-lane-contiguous bf16 fragments ----
__global__ void k_pack_w(const float* __restrict__ w, __hip_bfloat16* __restrict__ wp, int total) {
    int idx = blockIdx.x * blockDim.x + threadIdx.x;
    if (idx >= total) return;
    int j    = idx & 7;
    int lane = (idx >> 3) & 63;
    int n    = (idx >> 9) & 3;
    int h    = (idx >> 11) & 1;
    int rest = idx >> 12;
    int t    = rest % 27;
    int L    = rest / 27;
    int ic = h*32 + (lane >> 4)*8 + j;
    int oc = n*16 + (lane & 15);
    wp[idx] = __float2bfloat16(w[((size_t)(L*27 + t)*64 + ic)*64 + oc]);
}

// ---- dense 3x3x3 conv 64->64 via MFMA + BN + ReLU + mask, bf16 in/out ----
template<int DD>
__global__ __launch_bounds__(256) void k_conv64_mfma(
        const __hip_bfloat16* __restrict__ in, const __hip_bfloat16* __restrict__ wpL,
        const uint8_t* __restrict__ mask,
        const float* __restrict__ g, const float* __restrict__ b,
        const float* __restrict__ mn, const float* __restrict__ vr,
        __hip_bfloat16* __restrict__ out) {
    const int tid = threadIdx.x;
    const int w = tid >> 6, l = tid & 63;
    const int l15 = l & 15, kg = l >> 4;
    const int x0 = blockIdx.x * 32, yb = blockIdx.y * 8 + 2*w, z = blockIdx.z;

    f32x4 acc[4][4];
    #pragma unroll
    for (int f = 0; f < 4; ++f)
        #pragma unroll
        for (int n = 0; n < 4; ++n)
            acc[f][n] = (f32x4){0.f, 0.f, 0.f, 0.f};

    const bf16x8 az = {0,0,0,0,0,0,0,0};
    int t = 0;
    for (int kz = 0; kz < 3; ++kz) {
        const int zi = z + kz - 1;
        const bool zok = (zi >= 0) && (zi < DD);
        for (int ky = 0; ky < 3; ++ky) {
            for (int kx = 0; kx < 3; ++kx, ++t) {
                #pragma unroll
                for (int h = 0; h < 2; ++h) {
                    bf16x8 bfr[4];
                    const __hip_bfloat16* wb = wpL + (size_t)(t*2 + h)*2048 + (size_t)l*8;
                    #pragma unroll
                    for (int n = 0; n < 4; ++n)
                        bfr[n] = *reinterpret_cast<const bf16x8*>(wb + n*512);
                    bf16x8 afr[4];
                    #pragma unroll
                    for (int f = 0; f < 4; ++f) {
                        int yi = yb + (f >> 1) + ky - 1;
                        int xi = x0 + (f & 1)*16 + l15 + kx - 1;
                        bool ok = zok && (unsigned)yi < (unsigned)Hh && (unsigned)xi < (unsigned)Ww;
                        if (ok) {
                            const __hip_bfloat16* ap =
                                in + ((size_t)(zi*Hh + yi)*Ww + xi)*64 + h*32 + kg*8;
                            afr[f] = *reinterpret_cast<const bf16x8*>(ap);
                        } else {
                            afr[f] = az;
                        }
                    }
                    #pragma unroll
                    for (int f = 0; f < 4; ++f)
                        #pragma unroll
                        for (int n = 0; n < 4; ++n)
                            acc[f][n] = __builtin_amdgcn_mfma_f32_16x16x32_bf16(
                                afr[f], bfr[n], acc[f][n], 0, 0, 0);
                }
            }
        }
    }

    float sc[4], sh[4];
    #pragma unroll
    for (int n = 0; n < 4; ++n) {
        int oc = n*16 + l15;
        float s = g[oc] * rsqrtf(vr[oc] + EPS);
        sc[n] = s; sh[n] = b[oc] - mn[oc]*s;
    }
    #pragma unroll
    for (int f = 0; f < 4; ++f) {
        int yv = yb + (f >> 1);
        int xb2 = x0 + (f & 1)*16 + kg*4;
        #pragma unroll
        for (int r = 0; r < 4; ++r) {
            int vox = (z*Hh + yv)*Ww + (xb2 + r);
            bool mk = mask[vox] != 0;
            #pragma unroll
            for (int n = 0; n < 4; ++n) {
                float v = mk ? fmaxf(acc[f][n][r]*sc[n] + sh[n], 0.f) : 0.f;
                out[(size_t)vox*64 + n*16 + l15] = __float2bfloat16(v);
            }
        }
    }
}

// ---- pool2 z-pass (21 -> 10, no bounds) + occ OR from mk1 at c8==0 ----
__global__ void k_p2z(const short8* __restrict__ in, const uint8_t* __restrict__ mki,
                      short8* __restrict__ out, uint8_t* __restrict__ occ) {
    int t = blockIdx.x * blockDim.x + threadIdx.x;
    if (t >= D2*Hh*Ww*8) return;
    int c8 = t & 7, vox = t >> 3;
    int x = vox % Ww, y = (vox / Ww) % Hh, zo = vox / (Ww*Hh);
    short8 m = {0,0,0,0,0,0,0,0};   // values >= 0; masked cells are exact 0
    uint8_t o = 0;
    for (int dz = 0; dz < 3; ++dz) {
        int zi = 2*zo + dz;          // in [0,20] always
        int cv = (zi*Hh + y)*Ww + x;
        m = smax8(m, in[(size_t)cv*8 + c8]);
        if (c8 == 0) o |= mki[cv];
    }
    out[(size_t)vox*8 + c8] = m;
    if (c8 == 0) occ[vox] = o;
}

// ---- pool2 y-pass + occ OR ----
__global__ void k_p2y(const short8* __restrict__ in, const uint8_t* __restrict__ occi,
                      short8* __restrict__ out, uint8_t* __restrict__ occ) {
    int t = blockIdx.x * blockDim.x + threadIdx.x;
    if (t >= D2*Hh*Ww*8) return;
    int c8 = t & 7, vox = t >> 3;
    int x = vox % Ww, y = (vox / Ww) % Hh, zo = vox / (Ww*Hh);
    size_t base = (size_t)zo*Hh*Ww;
    short8 m = in[(base + (size_t)y*Ww + x)*8 + c8];
    uint8_t o = (c8 == 0) ? occi[base + (size_t)y*Ww + x] : 0;
    if (y > 0) {
        m = smax8(m, in[(base + (size_t)(y-1)*Ww + x)*8 + c8]);
        if (c8 == 0) o |= occi[base + (size_t)(y-1)*Ww + x];
    }
    if (y < Hh-1) {
        m = smax8(m, in[(base + (size_t)(y+1)*Ww + x)*8 + c8]);
        if (c8 == 0) o |= occi[base + (size_t)(y+1)*Ww + x];
    }
    out[(size_t)vox*8 + c8] = m;
    if (c8 == 0) occ[vox] = o;
}

// ---- pool2 x-pass + BN(row5) + ReLU + mk2 ----
__global__ void k_p2x(const short8* __restrict__ in, const uint8_t* __restrict__ occi,
                      const float* __restrict__ g, const float* __restrict__ b,
                      const float* __restrict__ mn, const float* __restrict__ vr,
                      short8* __restrict__ out, uint8_t* __restrict__ mk) {
    int t = blockIdx.x * blockDim.x + threadIdx.x;
    if (t >= D2*Hh*Ww*8) return;
    int c8 = t & 7, vox = t >> 3;
    int x = vox % Ww;
    short8 m = in[(size_t)vox*8 + c8];
    uint8_t occ = occi[vox];
    if (x > 0)    { m = smax8(m, in[(size_t)(vox-1)*8 + c8]); occ |= occi[vox-1]; }
    if (x < Ww-1) { m = smax8(m, in[(size_t)(vox+1)*8 + c8]); occ |= occi[vox+1]; }
    short8 o;
    #pragma unroll
    for (int j = 0; j < 8; ++j) {
        float v = 0.f;
        if (occ) {
            int c = c8*8 + j;
            float s = g[c] * rsqrtf(vr[c] + EPS);
            v = fmaxf(bfs2f(m[j])*s + (b[c] - mn[c]*s), 0.f);
        }
        o[j] = f2bfs(v);
    }
    out[(size_t)vox*8 + c8] = o;
    if (c8 == 0) mk[vox] = occ ? 1 : 0;
}

// ---- pool3 (3,1,1)/(2,1,1) + BN(row9) + ReLU + LDS transpose -> f32 (C*4,H,W) ----
__global__ __launch_bounds__(256) void k_pool3t(
        const short8* __restrict__ in, const uint8_t* __restrict__ mki,
        const float* __restrict__ g, const float* __restrict__ b,
        const float* __restrict__ mn, const float* __restrict__ vr,
        float* __restrict__ out) {
    __shared__ float lds[32][65];
    const int tid = threadIdx.x;
    const int x0 = blockIdx.x * 32, y = blockIdx.y, zo = blockIdx.z;
    {
        int xq = tid >> 3, c8 = tid & 7;
        int x = x0 + xq;
        short8 m = {0,0,0,0,0,0,0,0};
        bool occ = false;
        for (int dz = 0; dz < 3; ++dz) {
            int zi = 2*zo + dz;                  // max 8 < 10
            int cv = (zi*Hh + y)*Ww + x;
            m = smax8(m, in[(size_t)cv*8 + c8]);
            occ = occ || (mki[cv] != 0);
        }
        #pragma unroll
        for (int j = 0; j < 8; ++j) {
            float v = 0.f;
            if (occ) {
                int c = c8*8 + j;
                float s = g[c] * rsqrtf(vr[c] + EPS);
                v = fmaxf(bfs2f(m[j])*s + (b[c] - mn[c]*s), 0.f);
            }
            lds[xq][c8*8 + j] = v;
        }
    }
    __syncthreads();
    {
        int c = tid >> 2, xo = (tid & 3) * 8;
        size_t row = ((size_t)(c*4 + zo)*Hh + y)*Ww + x0 + xo;
        #pragma unroll
        for (int j = 0; j < 8; ++j)
            out[row + j] = lds[xo + j][c];
    }
}

extern "C" void kernel_launch(void* const* d_in, const int* in_sizes, int n_in,
                              void* d_out, int out_size, void* d_ws, size_t ws_size,
                              hipStream_t stream) {
    const float* vf    = (const float*)d_in[0];
    const int*   coors = (const int*)  d_in[1];
    const float* w_in  = (const float*)d_in[3];
    const float* w_up  = (const float*)d_in[4];
    const float* w_mid = (const float*)d_in[5];
    const float* bn0_g = (const float*)d_in[6];
    const float* bn0_b = (const float*)d_in[7];
    const float* bn0_m = (const float*)d_in[8];
    const float* bn0_v = (const float*)d_in[9];
    const float* bn_g  = (const float*)d_in[10];
    const float* bn_b  = (const float*)d_in[11];
    const float* bn_m  = (const float*)d_in[12];
    const float* bn_v  = (const float*)d_in[13];
    const int N = in_sizes[0] / 16;

    char* ws = (char*)d_ws;
    size_t off = 0;
    auto alloc = [&](size_t bytes) {
        void* p = ws + off;
        off = (off + bytes + 255) & ~(size_t)255;
        return p;
    };
    int*            map  = (int*)            alloc((size_t)Dd*Hh*Ww*4);
    float*          y1   = (float*)          alloc((size_t)N*32*4);
    float*          y2   = (float*)          alloc((size_t)N*64*4);
    uint8_t*        mk1  = (uint8_t*)        alloc((size_t)D1*Hh*Ww);
    uint8_t*        mk2  = (uint8_t*)        alloc((size_t)D2*Hh*Ww);
    uint8_t*        occa = (uint8_t*)        alloc((size_t)D2*Hh*Ww);
    uint8_t*        occb = (uint8_t*)        alloc((size_t)D2*Hh*Ww);
    __hip_bfloat16* wp   = (__hip_bfloat16*) alloc((size_t)6*27*2*4*64*8*2);
    short8*         A    = (short8*)         alloc((size_t)D1*Hh*Ww*64*2);
    short8*         B    = (short8*)         alloc((size_t)D1*Hh*Ww*64*2);
    // D2-grid views (32.768 MB each); two fit inside one D1 buffer (68.8 MB)
    const size_t D2G = (size_t)D2*Hh*Ww*64*2;            // bytes
    short8* p2a = A;
    short8* p2b = (short8*)((char*)A + D2G);
    short8* Bq  = B;   // pool2 output / conv ping
    short8* Aq  = A;   // conv pong / pool3 input

    const int PACK_TOTAL = 6*27*2*4*64*8;
    const size_t WPL = (size_t)27*2*4*64*8;
    const int P1T = D1*Hh*Ww*8, P2T = D2*Hh*Ww*8;

    hipMemsetAsync(map, 0xFF, (size_t)Dd*Hh*Ww*4, stream);
    k_pack_w<<<(PACK_TOTAL + 255)/256, 256, 0, stream>>>(w_mid, wp, PACK_TOTAL);
    k_scatter_winner<<<(N + 255)/256, 256, 0, stream>>>(coors, map, N);
    k_conv1<<<(N*32 + 255)/256, 256, 0, stream>>>(vf, coors, map, w_in,
            bn0_g, bn0_b, bn0_m, bn0_v, y1, N);
    k_conv2<<<(N*64 + 255)/256, 256, 0, stream>>>(y1, coors, map, w_up,
            bn_g, bn_b, bn_m, bn_v, y2, N);

    // pool1: z-gather (y2,map -> A), y (A -> B), x+BN (B -> A, mk1)
    k_p1zg<<<(P1T + 255)/256, 256, 0, stream>>>(y2, map, A);
    k_p1y <<<(P1T + 255)/256, 256, 0, stream>>>(A, B);
    k_p1x <<<(P1T + 255)/256, 256, 0, stream>>>(B,
            bn_g + 64, bn_b + 64, bn_m + 64, bn_v + 64, A, mk1);

    dim3 g1(Ww/32, Hh/8, D1);
    k_conv64_mfma<D1><<<g1, 256, 0, stream>>>((const __hip_bfloat16*)A, wp + 0*WPL, mk1,
            bn_g + 2*64, bn_b + 2*64, bn_m + 2*64, bn_v + 2*64, (__hip_bfloat16*)B);
    k_conv64_mfma<D1><<<g1, 256, 0, stream>>>((const __hip_bfloat16*)B, wp + 1*WPL, mk1,
            bn_g + 3*64, bn_b + 3*64, bn_m + 3*64, bn_v + 3*64, (__hip_bfloat16*)A);
    k_conv64_mfma<D1><<<g1, 256, 0, stream>>>((const __hip_bfloat16*)A, wp + 2*WPL, mk1,
            bn_g + 4*64, bn_b + 4*64, bn_m + 4*64, bn_v + 4*64, (__hip_bfloat16*)B);

    // pool2: z (B -> p2a in A, occa), y (p2a -> p2b, occb), x+BN (p2b -> Bq, mk2)
    k_p2z<<<(P2T + 255)/256, 256, 0, stream>>>(B, mk1, p2a, occa);
    k_p2y<<<(P2T + 255)/256, 256, 0, stream>>>(p2a, occa, p2b, occb);
    k_p2x<<<(P2T + 255)/256, 256, 0, stream>>>(p2b, occb,
            bn_g + 5*64, bn_b + 5*64, bn_m + 5*64, bn_v + 5*64, Bq, mk2);

    dim3 g2(Ww/32, Hh/8, D2);
    k_conv64_mfma<D2><<<g2, 256, 0, stream>>>((const __hip_bfloat16*)Bq, wp + 3*WPL, mk2,
            bn_g + 6*64, bn_b + 6*64, bn_m + 6*64, bn_v + 6*64, (__hip_bfloat16*)Aq);
    k_conv64_mfma<D2><<<g2, 256, 0, stream>>>((const __hip_bfloat16*)Aq, wp + 4*WPL, mk2,
            bn_g + 7*64, bn_b + 7*64, bn_m + 7*64, bn_v + 7*64, (__hip_bfloat16*)Bq);
    k_conv64_mfma<D2><<<g2, 256, 0, stream>>>((const __hip_bfloat16*)Bq, wp + 5*WPL, mk2,
            bn_g + 8*64, bn_b + 8*64, bn_m + 8*64, bn_v + 8*64, (__hip_bfloat16*)Aq);

    dim3 g3(Ww/32, Hh, 4);
    k_pool3t<<<g3, 256, 0, stream>>>(Aq, mk2,
            bn_g + 9*64, bn_b + 9*64, bn_m + 9*64, bn_v + 9*64, (float*)d_out);
}

// Round 11
// 1838.751 us; speedup vs baseline: 1.3827x; 1.0096x over previous
//
#include <hip/hip_runtime.h>
#include <hip/hip_bf16.h>
#include <stdint.h>

// SpMiddleNoDownsampleXYNoExpand on MI355X.
// sparse scatter -> subM conv(16->32) -> subM conv(32->64) [fp32]
// -> sparse z-gather pool1 + separable y/x -> 3x MFMA conv64 -> separable pool2
// -> 3x MFMA conv64 -> pool3(z)+transpose -> f32 out.
// R9: conv64 tap-nest fully unrolled + interior(no-bounds) fast path, lb(256,3).

#define EPS 1e-3f
constexpr int Dd = 41, Hh = 160, Ww = 160;
constexpr int D1 = 21, D2 = 10;

typedef short bf16x8 __attribute__((ext_vector_type(8)));
typedef short short8 __attribute__((ext_vector_type(8)));
typedef float f32x4  __attribute__((ext_vector_type(4)));

static __device__ __forceinline__ short f2bfs(float f) {
    __hip_bfloat16 h = __float2bfloat16(f);
    return *reinterpret_cast<short*>(&h);
}
static __device__ __forceinline__ float bfs2f(short s) {
    union { unsigned u; float f; } cv;
    cv.u = ((unsigned)(unsigned short)s) << 16;
    return cv.f;
}
static __device__ __forceinline__ short8 smax8(short8 a, short8 b) {
    short8 r;
    #pragma unroll
    for (int j = 0; j < 8; ++j) r[j] = a[j] > b[j] ? a[j] : b[j];
    return r;
}

// ---- winner scatter (last-write-wins == max voxel index) ----
__global__ void k_scatter_winner(const int* __restrict__ coors, int* __restrict__ map, int N) {
    int i = blockIdx.x * blockDim.x + threadIdx.x;
    if (i >= N) return;
    int z = coors[i*4+1], y = coors[i*4+2], x = coors[i*4+3];
    atomicMax(&map[(z*Hh + y)*Ww + x], i);
}

// ---- sparse submanifold conv 16->32 + BN0 + ReLU (fp32) ----
__global__ void k_conv1(const float* __restrict__ feat, const int* __restrict__ coors,
                        const int* __restrict__ map, const float* __restrict__ w,
                        const float* __restrict__ g, const float* __restrict__ b,
                        const float* __restrict__ mn, const float* __restrict__ vr,
                        float* __restrict__ y1, int N) {
    int t = blockIdx.x * blockDim.x + threadIdx.x;
    int i = t >> 5, oc = t & 31;
    if (i >= N) return;
    int z = coors[i*4+1], yy = coors[i*4+2], xx = coors[i*4+3];
    int cell = (z*Hh + yy)*Ww + xx;
    if (map[cell] != i) return;
    float acc = 0.f;
    for (int dz = 0; dz < 3; ++dz) {
        int nz = z + dz - 1; if (nz < 0 || nz >= Dd) continue;
        for (int dy = 0; dy < 3; ++dy) {
            int ny = yy + dy - 1; if (ny < 0 || ny >= Hh) continue;
            for (int dx = 0; dx < 3; ++dx) {
                int nx = xx + dx - 1; if (nx < 0 || nx >= Ww) continue;
                int j = map[(nz*Hh + ny)*Ww + nx];
                if (j < 0) continue;
                const float* f = feat + j*16;
                const float* wp = w + ((dz*3+dy)*3+dx)*(16*32) + oc;
                #pragma unroll
                for (int ic = 0; ic < 16; ++ic)
                    acc += f[ic] * wp[ic*32];
            }
        }
    }
    float s = g[oc] * rsqrtf(vr[oc] + EPS);
    y1[i*32 + oc] = fmaxf((acc - mn[oc]) * s + b[oc], 0.f);
}

// ---- sparse submanifold conv 32->64 + BN(row0) + ReLU (fp32) ----
__global__ void k_conv2(const float* __restrict__ y1, const int* __restrict__ coors,
                        const int* __restrict__ map, const float* __restrict__ w,
                        const float* __restrict__ g, const float* __restrict__ b,
                        const float* __restrict__ mn, const float* __restrict__ vr,
                        float* __restrict__ y2, int N) {
    int t = blockIdx.x * blockDim.x + threadIdx.x;
    int i = t >> 6, oc = t & 63;
    if (i >= N) return;
    int z = coors[i*4+1], yy = coors[i*4+2], xx = coors[i*4+3];
    int cell = (z*Hh + yy)*Ww + xx;
    if (map[cell] != i) return;
    float acc = 0.f;
    for (int dz = 0; dz < 3; ++dz) {
        int nz = z + dz - 1; if (nz < 0 || nz >= Dd) continue;
        for (int dy = 0; dy < 3; ++dy) {
            int ny = yy + dy - 1; if (ny < 0 || ny >= Hh) continue;
            for (int dx = 0; dx < 3; ++dx) {
                int nx = xx + dx - 1; if (nx < 0 || nx >= Ww) continue;
                int j = map[(nz*Hh + ny)*Ww + nx];
                if (j < 0) continue;
                const float* f = y1 + j*32;
                const float* wp = w + ((dz*3+dy)*3+dx)*(32*64) + oc;
                #pragma unroll
                for (int ic = 0; ic < 32; ++ic)
                    acc += f[ic] * wp[ic*64];
            }
        }
    }
    float s = g[oc] * rsqrtf(vr[oc] + EPS);
    y2[i*64 + oc] = fmaxf((acc - mn[oc]) * s + b[oc], 0.f);
}

// ---- pool1 z-pass as sparse gather: (41 -> 21) via map, winner rows of fp32 y2.
__global__ void k_p1zg(const float* __restrict__ y2, const int* __restrict__ map,
                       short8* __restrict__ out) {
    int t = blockIdx.x * blockDim.x + threadIdx.x;
    if (t >= D1*Hh*Ww*8) return;
    int c8 = t & 7, vox = t >> 3;
    int x = vox % Ww, y = (vox / Ww) % Hh, zo = vox / (Ww*Hh);
    float mv[8];
    #pragma unroll
    for (int q = 0; q < 8; ++q) mv[q] = 0.f;   // y2 >= 0 (post-ReLU)
    bool any = false;
    for (int dz = 0; dz < 3; ++dz) {
        int zi = 2*zo + dz - 1;
        if ((unsigned)zi >= (unsigned)Dd) continue;
        int j = map[(zi*Hh + y)*Ww + x];
        if (j < 0) continue;
        any = true;
        const float4* f = reinterpret_cast<const float4*>(y2 + (size_t)j*64 + c8*8);
        float4 a = f[0], b = f[1];
        mv[0] = fmaxf(mv[0], a.x); mv[1] = fmaxf(mv[1], a.y);
        mv[2] = fmaxf(mv[2], a.z); mv[3] = fmaxf(mv[3], a.w);
        mv[4] = fmaxf(mv[4], b.x); mv[5] = fmaxf(mv[5], b.y);
        mv[6] = fmaxf(mv[6], b.z); mv[7] = fmaxf(mv[7], b.w);
    }
    short8 o;
    #pragma unroll
    for (int q = 0; q < 8; ++q) o[q] = any ? f2bfs(mv[q]) : (short)0xFF80;
    out[(size_t)vox*8 + c8] = o;
}

// ---- pool1 y-pass (int16 max; -inf encodes empty) ----
__global__ void k_p1y(const short8* __restrict__ in, short8* __restrict__ out) {
    int t = blockIdx.x * blockDim.x + threadIdx.x;
    if (t >= D1*Hh*Ww*8) return;
    int c8 = t & 7, vox = t >> 3;
    int x = vox % Ww, y = (vox / Ww) % Hh, zo = vox / (Ww*Hh);
    size_t base = ((size_t)zo*Hh*Ww)*8;
    short8 m = in[base + ((size_t)y*Ww + x)*8 + c8];
    if (y > 0)      m = smax8(m, in[base + ((size_t)(y-1)*Ww + x)*8 + c8]);
    if (y < Hh-1)   m = smax8(m, in[base + ((size_t)(y+1)*Ww + x)*8 + c8]);
    out[(size_t)vox*8 + c8] = m;
}

// ---- pool1 x-pass + BN(row1) + ReLU + mask ----
__global__ void k_p1x(const short8* __restrict__ in,
                      const float* __restrict__ g, const float* __restrict__ b,
                      const float* __restrict__ mn, const float* __restrict__ vr,
                      short8* __restrict__ out, uint8_t* __restrict__ mk) {
    int t = blockIdx.x * blockDim.x + threadIdx.x;
    if (t >= D1*Hh*Ww*8) return;
    int c8 = t & 7, vox = t >> 3;
    int x = vox % Ww;
    short8 m = in[(size_t)vox*8 + c8];
    if (x > 0)      m = smax8(m, in[(size_t)(vox-1)*8 + c8]);
    if (x < Ww-1)   m = smax8(m, in[(size_t)(vox+1)*8 + c8]);
    bool occ = m[0] >= 0;     // occupied => all channels >= 0; empty => all -inf
    short8 o;
    #pragma unroll
    for (int j = 0; j < 8; ++j) {
        float v = 0.f;
        if (occ) {
            int c = c8*8 + j;
            float s = g[c] * rsqrtf(vr[c] + EPS);
            v = fmaxf(bfs2f(m[j])*s + (b[c] - mn[c]*s), 0.f);
        }
        o[j] = f2bfs(v);
    }
    out[(size_t)vox*8 + c8] = o;
    if (c8 == 0) mk[vox] = occ ? 1 : 0;
}

// ---- weight pack: w_mid[L][t][ic][oc] f32 -> per-lane-contiguous bf16 fragments ----
__global__ void k_pack_w(const float* __restrict__ w, __hip_bfloat16* __restrict__ wp, int total) {
    int idx = blockIdx.x * blockDim.x + threadIdx.x;
    if (idx >= total) return;
    int j    = idx & 7;
    int lane = (idx >> 3) & 63;
    int n    = (idx >> 9) & 3;
    int h    = (idx >> 11) & 1;
    int rest = idx >> 12;
    int t    = rest % 27;
    int L    = rest / 27;
    int ic = h*32 + (lane >> 4)*8 + j;
    int oc = n*16 + (lane & 15);
    wp[idx] = __float2bfloat16(w[((size_t)(L*27 + t)*64 + ic)*64 + oc]);
}

// ---- conv64 tap-nest body, templated on interior (no bounds checks) ----
template<int DD, bool INT>
__device__ __forceinline__ void conv_body(
        const __hip_bfloat16* __restrict__ in, const __hip_bfloat16* __restrict__ wpL,
        int x0, int yb, int z, int l15, int kg, int l, f32x4 (&acc)[4][4]) {
    const bf16x8 az = {0,0,0,0,0,0,0,0};
    #pragma unroll
    for (int kz = 0; kz < 3; ++kz) {
        const int zi = z + kz - 1;
        const bool zok = INT || ((zi >= 0) && (zi < DD));
        #pragma unroll
        for (int ky = 0; ky < 3; ++ky) {
            #pragma unroll
            for (int kx = 0; kx < 3; ++kx) {
                const int t = (kz*3 + ky)*3 + kx;
                #pragma unroll
                for (int h = 0; h < 2; ++h) {
                    bf16x8 bfr[4];
                    const __hip_bfloat16* wb = wpL + (size_t)(t*2 + h)*2048 + (size_t)l*8;
                    #pragma unroll
                    for (int n = 0; n < 4; ++n)
                        bfr[n] = *reinterpret_cast<const bf16x8*>(wb + n*512);
                    bf16x8 afr[4];
                    #pragma unroll
                    for (int f = 0; f < 4; ++f) {
                        int yi = yb + (f >> 1) + ky - 1;
                        int xi = x0 + (f & 1)*16 + l15 + kx - 1;
                        bool ok = INT || (zok && (unsigned)yi < (unsigned)Hh
                                              && (unsigned)xi < (unsigned)Ww);
                        if (ok) {
                            afr[f] = *reinterpret_cast<const bf16x8*>(
                                in + ((size_t)(zi*Hh + yi)*Ww + xi)*64 + h*32 + kg*8);
                        } else {
                            afr[f] = az;
                        }
                    }
                    #pragma unroll
                    for (int f = 0; f < 4; ++f)
                        #pragma unroll
                        for (int n = 0; n < 4; ++n)
                            acc[f][n] = __builtin_amdgcn_mfma_f32_16x16x32_bf16(
                                afr[f], bfr[n], acc[f][n], 0, 0, 0);
                }
            }
        }
    }
}

// ---- dense 3x3x3 conv 64->64 via MFMA + BN + ReLU + mask, bf16 in/out ----
// lb(256,3): cap VGPR ~170 -> 3 waves/SIMD while leaving slack for load-ahead.
template<int DD>
__global__ __launch_bounds__(256, 3) void k_conv64_mfma(
        const __hip_bfloat16* __restrict__ in, const __hip_bfloat16* __restrict__ wpL,
        const uint8_t* __restrict__ mask,
        const float* __restrict__ g, const float* __restrict__ b,
        const float* __restrict__ mn, const float* __restrict__ vr,
        __hip_bfloat16* __restrict__ out) {
    const int tid = threadIdx.x;
    const int w = tid >> 6, l = tid & 63;
    const int l15 = l & 15, kg = l >> 4;
    const int x0 = blockIdx.x * 32, yb = blockIdx.y * 8 + 2*w, z = blockIdx.z;

    f32x4 acc[4][4];
    #pragma unroll
    for (int f = 0; f < 4; ++f)
        #pragma unroll
        for (int n = 0; n < 4; ++n)
            acc[f][n] = (f32x4){0.f, 0.f, 0.f, 0.f};

    // interior (per-wave uniform): all 216 A-loads in bounds -> no predication
    const bool interior = (z >= 1) && (z + 2 <= DD)
                       && (yb >= 1) && (yb + 3 <= Hh)
                       && (x0 >= 1) && (x0 + 33 <= Ww);
    if (interior)
        conv_body<DD, true >(in, wpL, x0, yb, z, l15, kg, l, acc);
    else
        conv_body<DD, false>(in, wpL, x0, yb, z, l15, kg, l, acc);

    float sc[4], sh[4];
    #pragma unroll
    for (int n = 0; n < 4; ++n) {
        int oc = n*16 + l15;
        float s = g[oc] * rsqrtf(vr[oc] + EPS);
        sc[n] = s; sh[n] = b[oc] - mn[oc]*s;
    }
    #pragma unroll
    for (int f = 0; f < 4; ++f) {
        int yv = yb + (f >> 1);
        int xb2 = x0 + (f & 1)*16 + kg*4;
        #pragma unroll
        for (int r = 0; r < 4; ++r) {
            int vox = (z*Hh + yv)*Ww + (xb2 + r);
            bool mk = mask[vox] != 0;
            #pragma unroll
            for (int n = 0; n < 4; ++n) {
                float v = mk ? fmaxf(acc[f][n][r]*sc[n] + sh[n], 0.f) : 0.f;
                out[(size_t)vox*64 + n*16 + l15] = __float2bfloat16(v);
            }
        }
    }
}

// ---- pool2 z-pass (21 -> 10, no bounds) + occ OR from mk1 at c8==0 ----
__global__ void k_p2z(const short8* __restrict__ in, const uint8_t* __restrict__ mki,
                      short8* __restrict__ out, uint8_t* __restrict__ occ) {
    int t = blockIdx.x * blockDim.x + threadIdx.x;
    if (t >= D2*Hh*Ww*8) return;
    int c8 = t & 7, vox = t >> 3;
    int x = vox % Ww, y = (vox / Ww) % Hh, zo = vox / (Ww*Hh);
    short8 m = {0,0,0,0,0,0,0,0};   // values >= 0; masked cells are exact 0
    uint8_t o = 0;
    for (int dz = 0; dz < 3; ++dz) {
        int zi = 2*zo + dz;          // in [0,20] always
        int cv = (zi*Hh + y)*Ww + x;
        m = smax8(m, in[(size_t)cv*8 + c8]);
        if (c8 == 0) o |= mki[cv];
    }
    out[(size_t)vox*8 + c8] = m;
    if (c8 == 0) occ[vox] = o;
}

// ---- pool2 y-pass + occ OR ----
__global__ void k_p2y(const short8* __restrict__ in, const uint8_t* __restrict__ occi,
                      short8* __restrict__ out, uint8_t* __restrict__ occ) {
    int t = blockIdx.x * blockDim.x + threadIdx.x;
    if (t >= D2*Hh*Ww*8) return;
    int c8 = t & 7, vox = t >> 3;
    int x = vox % Ww, y = (vox / Ww) % Hh, zo = vox / (Ww*Hh);
    size_t base = (size_t)zo*Hh*Ww;
    short8 m = in[(base + (size_t)y*Ww + x)*8 + c8];
    uint8_t o = (c8 == 0) ? occi[base + (size_t)y*Ww + x] : 0;
    if (y > 0) {
        m = smax8(m, in[(base + (size_t)(y-1)*Ww + x)*8 + c8]);
        if (c8 == 0) o |= occi[base + (size_t)(y-1)*Ww + x];
    }
    if (y < Hh-1) {
        m = smax8(m, in[(base + (size_t)(y+1)*Ww + x)*8 + c8]);
        if (c8 == 0) o |= occi[base + (size_t)(y+1)*Ww + x];
    }
    out[(size_t)vox*8 + c8] = m;
    if (c8 == 0) occ[vox] = o;
}

// ---- pool2 x-pass + BN(row5) + ReLU + mk2 ----
__global__ void k_p2x(const short8* __restrict__ in, const uint8_t* __restrict__ occi,
                      const float* __restrict__ g, const float* __restrict__ b,
                      const float* __restrict__ mn, const float* __restrict__ vr,
                      short8* __restrict__ out, uint8_t* __restrict__ mk) {
    int t = blockIdx.x * blockDim.x + threadIdx.x;
    if (t >= D2*Hh*Ww*8) return;
    int c8 = t & 7, vox = t >> 3;
    int x = vox % Ww;
    short8 m = in[(size_t)vox*8 + c8];
    uint8_t occ = occi[vox];
    if (x > 0)    { m = smax8(m, in[(size_t)(vox-1)*8 + c8]); occ |= occi[vox-1]; }
    if (x < Ww-1) { m = smax8(m, in[(size_t)(vox+1)*8 + c8]); occ |= occi[vox+1]; }
    short8 o;
    #pragma unroll
    for (int j = 0; j < 8; ++j) {
        float v = 0.f;
        if (occ) {
            int c = c8*8 + j;
            float s = g[c] * rsqrtf(vr[c] + EPS);
            v = fmaxf(bfs2f(m[j])*s + (b[c] - mn[c]*s), 0.f);
        }
        o[j] = f2bfs(v);
    }
    out[(size_t)vox*8 + c8] = o;
    if (c8 == 0) mk[vox] = occ ? 1 : 0;
}

// ---- pool3 (3,1,1)/(2,1,1) + BN(row9) + ReLU + LDS transpose -> f32 (C*4,H,W) ----
__global__ __launch_bounds__(256) void k_pool3t(
        const short8* __restrict__ in, const uint8_t* __restrict__ mki,
        const float* __restrict__ g, const float* __restrict__ b,
        const float* __restrict__ mn, const float* __restrict__ vr,
        float* __restrict__ out) {
    __shared__ float lds[32][65];
    const int tid = threadIdx.x;
    const int x0 = blockIdx.x * 32, y = blockIdx.y, zo = blockIdx.z;
    {
        int xq = tid >> 3, c8 = tid & 7;
        int x = x0 + xq;
        short8 m = {0,0,0,0,0,0,0,0};
        bool occ = false;
        for (int dz = 0; dz < 3; ++dz) {
            int zi = 2*zo + dz;                  // max 8 < 10
            int cv = (zi*Hh + y)*Ww + x;
            m = smax8(m, in[(size_t)cv*8 + c8]);
            occ = occ || (mki[cv] != 0);
        }
        #pragma unroll
        for (int j = 0; j < 8; ++j) {
            float v = 0.f;
            if (occ) {
                int c = c8*8 + j;
                float s = g[c] * rsqrtf(vr[c] + EPS);
                v = fmaxf(bfs2f(m[j])*s + (b[c] - mn[c]*s), 0.f);
            }
            lds[xq][c8*8 + j] = v;
        }
    }
    __syncthreads();
    {
        int c = tid >> 2, xo = (tid & 3) * 8;
        size_t row = ((size_t)(c*4 + zo)*Hh + y)*Ww + x0 + xo;
        #pragma unroll
        for (int j = 0; j < 8; ++j)
            out[row + j] = lds[xo + j][c];
    }
}

extern "C" void kernel_launch(void* const* d_in, const int* in_sizes, int n_in,
                              void* d_out, int out_size, void* d_ws, size_t ws_size,
                              hipStream_t stream) {
    const float* vf    = (const float*)d_in[0];
    const int*   coors = (const int*)  d_in[1];
    const float* w_in  = (const float*)d_in[3];
    const float* w_up  = (const float*)d_in[4];
    const float* w_mid = (const float*)d_in[5];
    const float* bn0_g = (const float*)d_in[6];
    const float* bn0_b = (const float*)d_in[7];
    const float* bn0_m = (const float*)d_in[8];
    const float* bn0_v = (const float*)d_in[9];
    const float* bn_g  = (const float*)d_in[10];
    const float* bn_b  = (const float*)d_in[11];
    const float* bn_m  = (const float*)d_in[12];
    const float* bn_v  = (const float*)d_in[13];
    const int N = in_sizes[0] / 16;

    char* ws = (char*)d_ws;
    size_t off = 0;
    auto alloc = [&](size_t bytes) {
        void* p = ws + off;
        off = (off + bytes + 255) & ~(size_t)255;
        return p;
    };
    int*            map  = (int*)            alloc((size_t)Dd*Hh*Ww*4);
    float*          y1   = (float*)          alloc((size_t)N*32*4);
    float*          y2   = (float*)          alloc((size_t)N*64*4);
    uint8_t*        mk1  = (uint8_t*)        alloc((size_t)D1*Hh*Ww);
    uint8_t*        mk2  = (uint8_t*)        alloc((size_t)D2*Hh*Ww);
    uint8_t*        occa = (uint8_t*)        alloc((size_t)D2*Hh*Ww);
    uint8_t*        occb = (uint8_t*)        alloc((size_t)D2*Hh*Ww);
    __hip_bfloat16* wp   = (__hip_bfloat16*) alloc((size_t)6*27*2*4*64*8*2);
    short8*         A    = (short8*)         alloc((size_t)D1*Hh*Ww*64*2);
    short8*         B    = (short8*)         alloc((size_t)D1*Hh*Ww*64*2);
    // D2-grid views (32.768 MB each); two fit inside one D1 buffer (68.8 MB)
    const size_t D2G = (size_t)D2*Hh*Ww*64*2;            // bytes
    short8* p2a = A;
    short8* p2b = (short8*)((char*)A + D2G);
    short8* Bq  = B;   // pool2 output / conv ping
    short8* Aq  = A;   // conv pong / pool3 input

    const int PACK_TOTAL = 6*27*2*4*64*8;
    const size_t WPL = (size_t)27*2*4*64*8;
    const int P1T = D1*Hh*Ww*8, P2T = D2*Hh*Ww*8;

    hipMemsetAsync(map, 0xFF, (size_t)Dd*Hh*Ww*4, stream);
    k_pack_w<<<(PACK_TOTAL + 255)/256, 256, 0, stream>>>(w_mid, wp, PACK_TOTAL);
    k_scatter_winner<<<(N + 255)/256, 256, 0, stream>>>(coors, map, N);
    k_conv1<<<(N*32 + 255)/256, 256, 0, stream>>>(vf, coors, map, w_in,
            bn0_g, bn0_b, bn0_m, bn0_v, y1, N);
    k_conv2<<<(N*64 + 255)/256, 256, 0, stream>>>(y1, coors, map, w_up,
            bn_g, bn_b, bn_m, bn_v, y2, N);

    // pool1: z-gather (y2,map -> A), y (A -> B), x+BN (B -> A, mk1)
    k_p1zg<<<(P1T + 255)/256, 256, 0, stream>>>(y2, map, A);
    k_p1y <<<(P1T + 255)/256, 256, 0, stream>>>(A, B);
    k_p1x <<<(P1T + 255)/256, 256, 0, stream>>>(B,
            bn_g + 64, bn_b + 64, bn_m + 64, bn_v + 64, A, mk1);

    dim3 g1(Ww/32, Hh/8, D1);
    k_conv64_mfma<D1><<<g1, 256, 0, stream>>>((const __hip_bfloat16*)A, wp + 0*WPL, mk1,
            bn_g + 2*64, bn_b + 2*64, bn_m + 2*64, bn_v + 2*64, (__hip_bfloat16*)B);
    k_conv64_mfma<D1><<<g1, 256, 0, stream>>>((const __hip_bfloat16*)B, wp + 1*WPL, mk1,
            bn_g + 3*64, bn_b + 3*64, bn_m + 3*64, bn_v + 3*64, (__hip_bfloat16*)A);
    k_conv64_mfma<D1><<<g1, 256, 0, stream>>>((const __hip_bfloat16*)A, wp + 2*WPL, mk1,
            bn_g + 4*64, bn_b + 4*64, bn_m + 4*64, bn_v + 4*64, (__hip_bfloat16*)B);

    // pool2: z (B -> p2a in A, occa), y (p2a -> p2b, occb), x+BN (p2b -> Bq, mk2)
    k_p2z<<<(P2T + 255)/256, 256, 0, stream>>>(B, mk1, p2a, occa);
    k_p2y<<<(P2T + 255)/256, 256, 0, stream>>>(p2a, occa, p2b, occb);
    k_p2x<<<(P2T + 255)/256, 256, 0, stream>>>(p2b, occb,
            bn_g + 5*64, bn_b + 5*64, bn_m + 5*64, bn_v + 5*64, Bq, mk2);

    dim3 g2(Ww/32, Hh/8, D2);
    k_conv64_mfma<D2><<<g2, 256, 0, stream>>>((const __hip_bfloat16*)Bq, wp + 3*WPL, mk2,
            bn_g + 6*64, bn_b + 6*64, bn_m + 6*64, bn_v + 6*64, (__hip_bfloat16*)Aq);
    k_conv64_mfma<D2><<<g2, 256, 0, stream>>>((const __hip_bfloat16*)Aq, wp + 4*WPL, mk2,
            bn_g + 7*64, bn_b + 7*64, bn_m + 7*64, bn_v + 7*64, (__hip_bfloat16*)Bq);
    k_conv64_mfma<D2><<<g2, 256, 0, stream>>>((const __hip_bfloat16*)Bq, wp + 5*WPL, mk2,
            bn_g + 8*64, bn_b + 8*64, bn_m + 8*64, bn_v + 8*64, (__hip_bfloat16*)Aq);

    dim3 g3(Ww/32, Hh, 4);
    k_pool3t<<<g3, 256, 0, stream>>>(Aq, mk2,
            bn_g + 9*64, bn_b + 9*64, bn_m + 9*64, bn_v + 9*64, (float*)d_out);
}

// Round 12
// 1504.470 us; speedup vs baseline: 1.6900x; 1.2222x over previous
//
#include <hip/hip_runtime.h>
#include <hip/hip_bf16.h>
#include <stdint.h>

// SpMiddleNoDownsampleXYNoExpand on MI355X.
// sparse scatter -> subM conv(16->32) -> subM conv(32->64) [fp32]
// -> sparse z-gather pool1 + separable y/x -> 3x MFMA conv64 -> separable pool2
// -> 3x MFMA conv64 -> pool3(z)+transpose -> f32 out.
// R12: conv64 A-operands staged in LDS per kz-slice (slot-XOR swizzled),
//      OOB kz slices skipped; B stays L2. 43.5KB LDS -> 3 blocks/CU.

#define EPS 1e-3f
constexpr int Dd = 41, Hh = 160, Ww = 160;
constexpr int D1 = 21, D2 = 10;

typedef short bf16x8 __attribute__((ext_vector_type(8)));
typedef short short8 __attribute__((ext_vector_type(8)));
typedef float f32x4  __attribute__((ext_vector_type(4)));

static __device__ __forceinline__ short f2bfs(float f) {
    __hip_bfloat16 h = __float2bfloat16(f);
    return *reinterpret_cast<short*>(&h);
}
static __device__ __forceinline__ float bfs2f(short s) {
    union { unsigned u; float f; } cv;
    cv.u = ((unsigned)(unsigned short)s) << 16;
    return cv.f;
}
static __device__ __forceinline__ short8 smax8(short8 a, short8 b) {
    short8 r;
    #pragma unroll
    for (int j = 0; j < 8; ++j) r[j] = a[j] > b[j] ? a[j] : b[j];
    return r;
}

// ---- winner scatter (last-write-wins == max voxel index) ----
__global__ void k_scatter_winner(const int* __restrict__ coors, int* __restrict__ map, int N) {
    int i = blockIdx.x * blockDim.x + threadIdx.x;
    if (i >= N) return;
    int z = coors[i*4+1], y = coors[i*4+2], x = coors[i*4+3];
    atomicMax(&map[(z*Hh + y)*Ww + x], i);
}

// ---- sparse submanifold conv 16->32 + BN0 + ReLU (fp32) ----
__global__ void k_conv1(const float* __restrict__ feat, const int* __restrict__ coors,
                        const int* __restrict__ map, const float* __restrict__ w,
                        const float* __restrict__ g, const float* __restrict__ b,
                        const float* __restrict__ mn, const float* __restrict__ vr,
                        float* __restrict__ y1, int N) {
    int t = blockIdx.x * blockDim.x + threadIdx.x;
    int i = t >> 5, oc = t & 31;
    if (i >= N) return;
    int z = coors[i*4+1], yy = coors[i*4+2], xx = coors[i*4+3];
    int cell = (z*Hh + yy)*Ww + xx;
    if (map[cell] != i) return;
    float acc = 0.f;
    for (int dz = 0; dz < 3; ++dz) {
        int nz = z + dz - 1; if (nz < 0 || nz >= Dd) continue;
        for (int dy = 0; dy < 3; ++dy) {
            int ny = yy + dy - 1; if (ny < 0 || ny >= Hh) continue;
            for (int dx = 0; dx < 3; ++dx) {
                int nx = xx + dx - 1; if (nx < 0 || nx >= Ww) continue;
                int j = map[(nz*Hh + ny)*Ww + nx];
                if (j < 0) continue;
                const float* f = feat + j*16;
                const float* wp = w + ((dz*3+dy)*3+dx)*(16*32) + oc;
                #pragma unroll
                for (int ic = 0; ic < 16; ++ic)
                    acc += f[ic] * wp[ic*32];
            }
        }
    }
    float s = g[oc] * rsqrtf(vr[oc] + EPS);
    y1[i*32 + oc] = fmaxf((acc - mn[oc]) * s + b[oc], 0.f);
}

// ---- sparse submanifold conv 32->64 + BN(row0) + ReLU (fp32) ----
__global__ void k_conv2(const float* __restrict__ y1, const int* __restrict__ coors,
                        const int* __restrict__ map, const float* __restrict__ w,
                        const float* __restrict__ g, const float* __restrict__ b,
                        const float* __restrict__ mn, const float* __restrict__ vr,
                        float* __restrict__ y2, int N) {
    int t = blockIdx.x * blockDim.x + threadIdx.x;
    int i = t >> 6, oc = t & 63;
    if (i >= N) return;
    int z = coors[i*4+1], yy = coors[i*4+2], xx = coors[i*4+3];
    int cell = (z*Hh + yy)*Ww + xx;
    if (map[cell] != i) return;
    float acc = 0.f;
    for (int dz = 0; dz < 3; ++dz) {
        int nz = z + dz - 1; if (nz < 0 || nz >= Dd) continue;
        for (int dy = 0; dy < 3; ++dy) {
            int ny = yy + dy - 1; if (ny < 0 || ny >= Hh) continue;
            for (int dx = 0; dx < 3; ++dx) {
                int nx = xx + dx - 1; if (nx < 0 || nx >= Ww) continue;
                int j = map[(nz*Hh + ny)*Ww + nx];
                if (j < 0) continue;
                const float* f = y1 + j*32;
                const float* wp = w + ((dz*3+dy)*3+dx)*(32*64) + oc;
                #pragma unroll
                for (int ic = 0; ic < 32; ++ic)
                    acc += f[ic] * wp[ic*64];
            }
        }
    }
    float s = g[oc] * rsqrtf(vr[oc] + EPS);
    y2[i*64 + oc] = fmaxf((acc - mn[oc]) * s + b[oc], 0.f);
}

// ---- pool1 z-pass as sparse gather: (41 -> 21) via map, winner rows of fp32 y2.
__global__ void k_p1zg(const float* __restrict__ y2, const int* __restrict__ map,
                       short8* __restrict__ out) {
    int t = blockIdx.x * blockDim.x + threadIdx.x;
    if (t >= D1*Hh*Ww*8) return;
    int c8 = t & 7, vox = t >> 3;
    int x = vox % Ww, y = (vox / Ww) % Hh, zo = vox / (Ww*Hh);
    float mv[8];
    #pragma unroll
    for (int q = 0; q < 8; ++q) mv[q] = 0.f;   // y2 >= 0 (post-ReLU)
    bool any = false;
    for (int dz = 0; dz < 3; ++dz) {
        int zi = 2*zo + dz - 1;
        if ((unsigned)zi >= (unsigned)Dd) continue;
        int j = map[(zi*Hh + y)*Ww + x];
        if (j < 0) continue;
        any = true;
        const float4* f = reinterpret_cast<const float4*>(y2 + (size_t)j*64 + c8*8);
        float4 a = f[0], b = f[1];
        mv[0] = fmaxf(mv[0], a.x); mv[1] = fmaxf(mv[1], a.y);
        mv[2] = fmaxf(mv[2], a.z); mv[3] = fmaxf(mv[3], a.w);
        mv[4] = fmaxf(mv[4], b.x); mv[5] = fmaxf(mv[5], b.y);
        mv[6] = fmaxf(mv[6], b.z); mv[7] = fmaxf(mv[7], b.w);
    }
    short8 o;
    #pragma unroll
    for (int q = 0; q < 8; ++q) o[q] = any ? f2bfs(mv[q]) : (short)0xFF80;
    out[(size_t)vox*8 + c8] = o;
}

// ---- pool1 y-pass (int16 max; -inf encodes empty) ----
__global__ void k_p1y(const short8* __restrict__ in, short8* __restrict__ out) {
    int t = blockIdx.x * blockDim.x + threadIdx.x;
    if (t >= D1*Hh*Ww*8) return;
    int c8 = t & 7, vox = t >> 3;
    int x = vox % Ww, y = (vox / Ww) % Hh, zo = vox / (Ww*Hh);
    size_t base = ((size_t)zo*Hh*Ww)*8;
    short8 m = in[base + ((size_t)y*Ww + x)*8 + c8];
    if (y > 0)      m = smax8(m, in[base + ((size_t)(y-1)*Ww + x)*8 + c8]);
    if (y < Hh-1)   m = smax8(m, in[base + ((size_t)(y+1)*Ww + x)*8 + c8]);
    out[(size_t)vox*8 + c8] = m;
}

// ---- pool1 x-pass + BN(row1) + ReLU + mask ----
__global__ void k_p1x(const short8* __restrict__ in,
                      const float* __restrict__ g, const float* __restrict__ b,
                      const float* __restrict__ mn, const float* __restrict__ vr,
                      short8* __restrict__ out, uint8_t* __restrict__ mk) {
    int t = blockIdx.x * blockDim.x + threadIdx.x;
    if (t >= D1*Hh*Ww*8) return;
    int c8 = t & 7, vox = t >> 3;
    int x = vox % Ww;
    short8 m = in[(size_t)vox*8 + c8];
    if (x > 0)      m = smax8(m, in[(size_t)(vox-1)*8 + c8]);
    if (x < Ww-1)   m = smax8(m, in[(size_t)(vox+1)*8 + c8]);
    bool occ = m[0] >= 0;     // occupied => all channels >= 0; empty => all -inf
    short8 o;
    #pragma unroll
    for (int j = 0; j < 8; ++j) {
        float v = 0.f;
        if (occ) {
            int c = c8*8 + j;
            float s = g[c] * rsqrtf(vr[c] + EPS);
            v = fmaxf(bfs2f(m[j])*s + (b[c] - mn[c]*s), 0.f);
        }
        o[j] = f2bfs(v);
    }
    out[(size_t)vox*8 + c8] = o;
    if (c8 == 0) mk[vox] = occ ? 1 : 0;
}

// ---- weight pack: w_mid[L][t][ic][oc] f32 -> per-lane-contiguous bf16 fragments ----
__global__ void k_pack_w(const float* __restrict__ w, __hip_bfloat16* __restrict__ wp, int total) {
    int idx = blockIdx.x * blockDim.x + threadIdx.x;
    if (idx >= total) return;
    int j    = idx & 7;
    int lane = (idx >> 3) & 63;
    int n    = (idx >> 9) & 3;
    int h    = (idx >> 11) & 1;
    int rest = idx >> 12;
    int t    = rest % 27;
    int L    = rest / 27;
    int ic = h*32 + (lane >> 4)*8 + j;
    int oc = n*16 + (lane & 15);
    wp[idx] = __float2bfloat16(w[((size_t)(L*27 + t)*64 + ic)*64 + oc]);
}

// ---- dense 3x3x3 conv 64->64 via MFMA, A staged in LDS per kz-slice ----
// Block 256 thr = 4 waves, tile 32x*8y*1z. LDS slice: [10 ly][34 lx][8 slots]
// of 16B (43.5KB), slot index XOR'd with (lx&7) for bank balance.
template<int DD>
__global__ __launch_bounds__(256, 3) void k_conv64_mfma(
        const __hip_bfloat16* __restrict__ in, const __hip_bfloat16* __restrict__ wpL,
        const uint8_t* __restrict__ mask,
        const float* __restrict__ g, const float* __restrict__ b,
        const float* __restrict__ mn, const float* __restrict__ vr,
        __hip_bfloat16* __restrict__ out) {
    __shared__ short8 sA[10*34*8];          // 43,520 B
    const int tid = threadIdx.x;
    const int w = tid >> 6, l = tid & 63;
    const int l15 = l & 15, kg = l >> 4;
    const int x0 = blockIdx.x * 32, y0 = blockIdx.y * 8, z = blockIdx.z;
    const int yb = y0 + 2*w;

    f32x4 acc[4][4];
    #pragma unroll
    for (int f = 0; f < 4; ++f)
        #pragma unroll
        for (int n = 0; n < 4; ++n)
            acc[f][n] = (f32x4){0.f, 0.f, 0.f, 0.f};

    for (int kz = 0; kz < 3; ++kz) {
        const int zi = z + kz - 1;
        if (zi < 0 || zi >= DD) continue;      // block-uniform: OOB slice = zero contrib
        __syncthreads();                        // previous slice's compute done
        // ---- stage slice zi: 10*34 voxels * 8 slots of 16B, reg-staged ----
        for (int c = tid; c < 2720; c += 256) {
            int v = c >> 3, s = c & 7;
            int ly = v / 34, lx = v - ly*34;
            int gy = y0 - 1 + ly, gx = x0 - 1 + lx;
            bf16x8 val = {0,0,0,0,0,0,0,0};
            if ((unsigned)gy < (unsigned)Hh && (unsigned)gx < (unsigned)Ww)
                val = *reinterpret_cast<const bf16x8*>(
                        in + ((size_t)(zi*Hh + gy)*Ww + gx)*64 + s*8);
            sA[v*8 + (s ^ (lx & 7))] = val;
        }
        __syncthreads();
        // ---- 9 taps x 2 ic-halves from LDS ----
        #pragma unroll
        for (int ky = 0; ky < 3; ++ky) {
            #pragma unroll
            for (int kx = 0; kx < 3; ++kx) {
                const int t = (kz*3 + ky)*3 + kx;
                #pragma unroll
                for (int h = 0; h < 2; ++h) {
                    bf16x8 bfr[4];
                    const __hip_bfloat16* wb = wpL + (size_t)(t*2 + h)*2048 + (size_t)l*8;
                    #pragma unroll
                    for (int n = 0; n < 4; ++n)
                        bfr[n] = *reinterpret_cast<const bf16x8*>(wb + n*512);
                    bf16x8 afr[4];
                    #pragma unroll
                    for (int f = 0; f < 4; ++f) {
                        int ly = 2*w + (f >> 1) + ky;
                        int lx = (f & 1)*16 + l15 + kx;
                        afr[f] = sA[(ly*34 + lx)*8 + ((h*4 + kg) ^ (lx & 7))];
                    }
                    #pragma unroll
                    for (int f = 0; f < 4; ++f)
                        #pragma unroll
                        for (int n = 0; n < 4; ++n)
                            acc[f][n] = __builtin_amdgcn_mfma_f32_16x16x32_bf16(
                                afr[f], bfr[n], acc[f][n], 0, 0, 0);
                }
            }
        }
    }

    float sc[4], sh[4];
    #pragma unroll
    for (int n = 0; n < 4; ++n) {
        int oc = n*16 + l15;
        float s = g[oc] * rsqrtf(vr[oc] + EPS);
        sc[n] = s; sh[n] = b[oc] - mn[oc]*s;
    }
    #pragma unroll
    for (int f = 0; f < 4; ++f) {
        int yv = yb + (f >> 1);
        int xb2 = x0 + (f & 1)*16 + kg*4;
        #pragma unroll
        for (int r = 0; r < 4; ++r) {
            int vox = (z*Hh + yv)*Ww + (xb2 + r);
            bool mk = mask[vox] != 0;
            #pragma unroll
            for (int n = 0; n < 4; ++n) {
                float v = mk ? fmaxf(acc[f][n][r]*sc[n] + sh[n], 0.f) : 0.f;
                out[(size_t)vox*64 + n*16 + l15] = __float2bfloat16(v);
            }
        }
    }
}

// ---- pool2 z-pass (21 -> 10, no bounds) + occ OR from mk1 at c8==0 ----
__global__ void k_p2z(const short8* __restrict__ in, const uint8_t* __restrict__ mki,
                      short8* __restrict__ out, uint8_t* __restrict__ occ) {
    int t = blockIdx.x * blockDim.x + threadIdx.x;
    if (t >= D2*Hh*Ww*8) return;
    int c8 = t & 7, vox = t >> 3;
    int x = vox % Ww, y = (vox / Ww) % Hh, zo = vox / (Ww*Hh);
    short8 m = {0,0,0,0,0,0,0,0};   // values >= 0; masked cells are exact 0
    uint8_t o = 0;
    for (int dz = 0; dz < 3; ++dz) {
        int zi = 2*zo + dz;          // in [0,20] always
        int cv = (zi*Hh + y)*Ww + x;
        m = smax8(m, in[(size_t)cv*8 + c8]);
        if (c8 == 0) o |= mki[cv];
    }
    out[(size_t)vox*8 + c8] = m;
    if (c8 == 0) occ[vox] = o;
}

// ---- pool2 y-pass + occ OR ----
__global__ void k_p2y(const short8* __restrict__ in, const uint8_t* __restrict__ occi,
                      short8* __restrict__ out, uint8_t* __restrict__ occ) {
    int t = blockIdx.x * blockDim.x + threadIdx.x;
    if (t >= D2*Hh*Ww*8) return;
    int c8 = t & 7, vox = t >> 3;
    int x = vox % Ww, y = (vox / Ww) % Hh, zo = vox / (Ww*Hh);
    size_t base = (size_t)zo*Hh*Ww;
    short8 m = in[(base + (size_t)y*Ww + x)*8 + c8];
    uint8_t o = (c8 == 0) ? occi[base + (size_t)y*Ww + x] : 0;
    if (y > 0) {
        m = smax8(m, in[(base + (size_t)(y-1)*Ww + x)*8 + c8]);
        if (c8 == 0) o |= occi[base + (size_t)(y-1)*Ww + x];
    }
    if (y < Hh-1) {
        m = smax8(m, in[(base + (size_t)(y+1)*Ww + x)*8 + c8]);
        if (c8 == 0) o |= occi[base + (size_t)(y+1)*Ww + x];
    }
    out[(size_t)vox*8 + c8] = m;
    if (c8 == 0) occ[vox] = o;
}

// ---- pool2 x-pass + BN(row5) + ReLU + mk2 ----
__global__ void k_p2x(const short8* __restrict__ in, const uint8_t* __restrict__ occi,
                      const float* __restrict__ g, const float* __restrict__ b,
                      const float* __restrict__ mn, const float* __restrict__ vr,
                      short8* __restrict__ out, uint8_t* __restrict__ mk) {
    int t = blockIdx.x * blockDim.x + threadIdx.x;
    if (t >= D2*Hh*Ww*8) return;
    int c8 = t & 7, vox = t >> 3;
    int x = vox % Ww;
    short8 m = in[(size_t)vox*8 + c8];
    uint8_t occ = occi[vox];
    if (x > 0)    { m = smax8(m, in[(size_t)(vox-1)*8 + c8]); occ |= occi[vox-1]; }
    if (x < Ww-1) { m = smax8(m, in[(size_t)(vox+1)*8 + c8]); occ |= occi[vox+1]; }
    short8 o;
    #pragma unroll
    for (int j = 0; j < 8; ++j) {
        float v = 0.f;
        if (occ) {
            int c = c8*8 + j;
            float s = g[c] * rsqrtf(vr[c] + EPS);
            v = fmaxf(bfs2f(m[j])*s + (b[c] - mn[c]*s), 0.f);
        }
        o[j] = f2bfs(v);
    }
    out[(size_t)vox*8 + c8] = o;
    if (c8 == 0) mk[vox] = occ ? 1 : 0;
}

// ---- pool3 (3,1,1)/(2,1,1) + BN(row9) + ReLU + LDS transpose -> f32 (C*4,H,W) ----
__global__ __launch_bounds__(256) void k_pool3t(
        const short8* __restrict__ in, const uint8_t* __restrict__ mki,
        const float* __restrict__ g, const float* __restrict__ b,
        const float* __restrict__ mn, const float* __restrict__ vr,
        float* __restrict__ out) {
    __shared__ float lds[32][65];
    const int tid = threadIdx.x;
    const int x0 = blockIdx.x * 32, y = blockIdx.y, zo = blockIdx.z;
    {
        int xq = tid >> 3, c8 = tid & 7;
        int x = x0 + xq;
        short8 m = {0,0,0,0,0,0,0,0};
        bool occ = false;
        for (int dz = 0; dz < 3; ++dz) {
            int zi = 2*zo + dz;                  // max 8 < 10
            int cv = (zi*Hh + y)*Ww + x;
            m = smax8(m, in[(size_t)cv*8 + c8]);
            occ = occ || (mki[cv] != 0);
        }
        #pragma unroll
        for (int j = 0; j < 8; ++j) {
            float v = 0.f;
            if (occ) {
                int c = c8*8 + j;
                float s = g[c] * rsqrtf(vr[c] + EPS);
                v = fmaxf(bfs2f(m[j])*s + (b[c] - mn[c]*s), 0.f);
            }
            lds[xq][c8*8 + j] = v;
        }
    }
    __syncthreads();
    {
        int c = tid >> 2, xo = (tid & 3) * 8;
        size_t row = ((size_t)(c*4 + zo)*Hh + y)*Ww + x0 + xo;
        #pragma unroll
        for (int j = 0; j < 8; ++j)
            out[row + j] = lds[xo + j][c];
    }
}

extern "C" void kernel_launch(void* const* d_in, const int* in_sizes, int n_in,
                              void* d_out, int out_size, void* d_ws, size_t ws_size,
                              hipStream_t stream) {
    const float* vf    = (const float*)d_in[0];
    const int*   coors = (const int*)  d_in[1];
    const float* w_in  = (const float*)d_in[3];
    const float* w_up  = (const float*)d_in[4];
    const float* w_mid = (const float*)d_in[5];
    const float* bn0_g = (const float*)d_in[6];
    const float* bn0_b = (const float*)d_in[7];
    const float* bn0_m = (const float*)d_in[8];
    const float* bn0_v = (const float*)d_in[9];
    const float* bn_g  = (const float*)d_in[10];
    const float* bn_b  = (const float*)d_in[11];
    const float* bn_m  = (const float*)d_in[12];
    const float* bn_v  = (const float*)d_in[13];
    const int N = in_sizes[0] / 16;

    char* ws = (char*)d_ws;
    size_t off = 0;
    auto alloc = [&](size_t bytes) {
        void* p = ws + off;
        off = (off + bytes + 255) & ~(size_t)255;
        return p;
    };
    int*            map  = (int*)            alloc((size_t)Dd*Hh*Ww*4);
    float*          y1   = (float*)          alloc((size_t)N*32*4);
    float*          y2   = (float*)          alloc((size_t)N*64*4);
    uint8_t*        mk1  = (uint8_t*)        alloc((size_t)D1*Hh*Ww);
    uint8_t*        mk2  = (uint8_t*)        alloc((size_t)D2*Hh*Ww);
    uint8_t*        occa = (uint8_t*)        alloc((size_t)D2*Hh*Ww);
    uint8_t*        occb = (uint8_t*)        alloc((size_t)D2*Hh*Ww);
    __hip_bfloat16* wp   = (__hip_bfloat16*) alloc((size_t)6*27*2*4*64*8*2);
    short8*         A    = (short8*)         alloc((size_t)D1*Hh*Ww*64*2);
    short8*         B    = (short8*)         alloc((size_t)D1*Hh*Ww*64*2);
    // D2-grid views (32.768 MB each); two fit inside one D1 buffer (68.8 MB)
    const size_t D2G = (size_t)D2*Hh*Ww*64*2;            // bytes
    short8* p2a = A;
    short8* p2b = (short8*)((char*)A + D2G);
    short8* Bq  = B;   // pool2 output / conv ping
    short8* Aq  = A;   // conv pong / pool3 input

    const int PACK_TOTAL = 6*27*2*4*64*8;
    const size_t WPL = (size_t)27*2*4*64*8;
    const int P1T = D1*Hh*Ww*8, P2T = D2*Hh*Ww*8;

    hipMemsetAsync(map, 0xFF, (size_t)Dd*Hh*Ww*4, stream);
    k_pack_w<<<(PACK_TOTAL + 255)/256, 256, 0, stream>>>(w_mid, wp, PACK_TOTAL);
    k_scatter_winner<<<(N + 255)/256, 256, 0, stream>>>(coors, map, N);
    k_conv1<<<(N*32 + 255)/256, 256, 0, stream>>>(vf, coors, map, w_in,
            bn0_g, bn0_b, bn0_m, bn0_v, y1, N);
    k_conv2<<<(N*64 + 255)/256, 256, 0, stream>>>(y1, coors, map, w_up,
            bn_g, bn_b, bn_m, bn_v, y2, N);

    // pool1: z-gather (y2,map -> A), y (A -> B), x+BN (B -> A, mk1)
    k_p1zg<<<(P1T + 255)/256, 256, 0, stream>>>(y2, map, A);
    k_p1y <<<(P1T + 255)/256, 256, 0, stream>>>(A, B);
    k_p1x <<<(P1T + 255)/256, 256, 0, stream>>>(B,
            bn_g + 64, bn_b + 64, bn_m + 64, bn_v + 64, A, mk1);

    dim3 g1(Ww/32, Hh/8, D1);
    k_conv64_mfma<D1><<<g1, 256, 0, stream>>>((const __hip_bfloat16*)A, wp + 0*WPL, mk1,
            bn_g + 2*64, bn_b + 2*64, bn_m + 2*64, bn_v + 2*64, (__hip_bfloat16*)B);
    k_conv64_mfma<D1><<<g1, 256, 0, stream>>>((const __hip_bfloat16*)B, wp + 1*WPL, mk1,
            bn_g + 3*64, bn_b + 3*64, bn_m + 3*64, bn_v + 3*64, (__hip_bfloat16*)A);
    k_conv64_mfma<D1><<<g1, 256, 0, stream>>>((const __hip_bfloat16*)A, wp + 2*WPL, mk1,
            bn_g + 4*64, bn_b + 4*64, bn_m + 4*64, bn_v + 4*64, (__hip_bfloat16*)B);

    // pool2: z (B -> p2a in A, occa), y (p2a -> p2b, occb), x+BN (p2b -> Bq, mk2)
    k_p2z<<<(P2T + 255)/256, 256, 0, stream>>>(B, mk1, p2a, occa);
    k_p2y<<<(P2T + 255)/256, 256, 0, stream>>>(p2a, occa, p2b, occb);
    k_p2x<<<(P2T + 255)/256, 256, 0, stream>>>(p2b, occb,
            bn_g + 5*64, bn_b + 5*64, bn_m + 5*64, bn_v + 5*64, Bq, mk2);

    dim3 g2(Ww/32, Hh/8, D2);
    k_conv64_mfma<D2><<<g2, 256, 0, stream>>>((const __hip_bfloat16*)Bq, wp + 3*WPL, mk2,
            bn_g + 6*64, bn_b + 6*64, bn_m + 6*64, bn_v + 6*64, (__hip_bfloat16*)Aq);
    k_conv64_mfma<D2><<<g2, 256, 0, stream>>>((const __hip_bfloat16*)Aq, wp + 4*WPL, mk2,
            bn_g + 7*64, bn_b + 7*64, bn_m + 7*64, bn_v + 7*64, (__hip_bfloat16*)Bq);
    k_conv64_mfma<D2><<<g2, 256, 0, stream>>>((const __hip_bfloat16*)Bq, wp + 5*WPL, mk2,
            bn_g + 8*64, bn_b + 8*64, bn_m + 8*64, bn_v + 8*64, (__hip_bfloat16*)Aq);

    dim3 g3(Ww/32, Hh, 4);
    k_pool3t<<<g3, 256, 0, stream>>>(Aq, mk2,
            bn_g + 9*64, bn_b + 9*64, bn_m + 9*64, bn_v + 9*64, (float*)d_out);
}